// Round 9
// baseline (164.491 us; speedup 1.0000x reference)
//
#include <hip/hip_runtime.h>

// DigiCaps dynamic routing — R27: load-all-then-compute + sched_barrier(0)
// on the R24/R26 substrate (no LDS, no barriers, (256,1)).
// inputs [512,1152,8] f32, W [10,1152,16,8] f32, out v [512,10,16] f32.
// u_hat[b,j,i,d] = sum_k x[b,i,k] W[j,i,d,k]; logits via vsum recurrence;
// u_hat never materialized (3 recompute passes).
//
// Evidence trail (21 variants, caps 41-47us ALWAYS):
//  Flat vs: block count 288-2304, per-block work 0.5-4x, read bytes 8-16MB
//  (R25), LDS vs direct (R24), barriers vs none, VGPR budget 128 vs 256
//  (R26). R20/R21 spills = artifacts (gate: FETCH <= ~25MB).
// Surviving theory (fits wave-lifetime data): wave lifetime ~14.6us
// (R18) ~= 800cy PER MEMORY OP — loads execute SERIALLY (compiler emits
// load->wait->mfma per j, zero MLP). R25's per-unit wave latency halved
// (6.8 vs 14.6us) when W loads amortized = exactly what a serial-load-
// chain model predicts; total stayed flat only because residency dropped.
// R27: issue ALL loads (afull[2][10], xv[2], vs[10]) into registers in one
// phase; __builtin_amdgcn_sched_barrier(0) pins them before any compute;
// one vmcnt covers ~22-32 in-flight loads -> critical path ~900cy total.
// All indices compile-time (full unroll; runtime-indexed ext_vector goes
// to scratch). VGPR est ~200-235 of 256. Spill gate: FETCH <= 25MB.
// Carried: MFMA f32_16x16x32_bf16 (C: lane&15=b, (lane>>4)*4+reg=d);
// K=32 packs 4 i's (all lanes real); MODE1 masks B per q; fp16x2 logit
// butterfly; no max-subtract; bf16 pre-convert; part 144 slabs + proven
// squash_reduce. absmax prior 3.9e-3 (threshold 17.5e-3).

#define NB 512
#define NI 1152
#define NJ 10
#define ND 16
#define NIGB 144   // i-groups of 8

typedef short          bf16x8 __attribute__((ext_vector_type(8)));
typedef unsigned short u16x8  __attribute__((ext_vector_type(8)));
typedef float          f32x4  __attribute__((ext_vector_type(4)));
typedef __fp16         h16x2  __attribute__((ext_vector_type(2)));

constexpr float EPS_ = 1e-7f;

constexpr size_t XB_ELEMS = (size_t)NB * NI * 8;       // bf16
constexpr size_t WB_ELEMS = (size_t)NJ * NI * ND * 8;  // bf16
constexpr int    XQ = 1179648;                         // x float4 quads
constexpr int    WQ = 368640;                          // W float4 quads

__device__ inline unsigned short f2bf(float f) {   // RNE f32->bf16
    unsigned u = __float_as_uint(f);
    return (unsigned short)((u + 0x7fffu + ((u >> 16) & 1u)) >> 16);
}
__device__ inline float bf2f(unsigned short u) {
    return __uint_as_float((unsigned)u << 16);
}

__global__ __launch_bounds__(256)
void conv_bf16(const float* __restrict__ x, const float* __restrict__ Wg,
               unsigned short* __restrict__ xb, unsigned short* __restrict__ wb)
{
    int t = blockIdx.x * 256 + threadIdx.x;
    if (t < XQ) {
        float4 v = ((const float4*)x)[t];
        ushort4 o; o.x=f2bf(v.x); o.y=f2bf(v.y); o.z=f2bf(v.z); o.w=f2bf(v.w);
        ((ushort4*)xb)[t] = o;
    } else if (t - XQ < WQ) {
        int u = t - XQ;
        float4 v = ((const float4*)Wg)[u];
        ushort4 o; o.x=f2bf(v.x); o.y=f2bf(v.y); o.z=f2bf(v.z); o.w=f2bf(v.w);
        ((ushort4*)wb)[u] = o;
    }
}

// Block: 4 independent waves; each wave owns 16 b x 8 i. No LDS, no
// barriers. PHASE 1 issues every global load; sched_barrier(0) pins them
// before PHASE 2 compute so one vmcnt covers all loads in flight.
// wb layout [j][i][d][k]: granule (16B) addr = ((j*NI + i)*16 + d) * 8 shorts.
template <int MODE>
__global__ __launch_bounds__(256, 1)
void caps_pass(const unsigned short* __restrict__ xb,
               const unsigned short* __restrict__ wb,
               const float* __restrict__ vsum_g,
               unsigned short* __restrict__ part)
{
    const int tid = threadIdx.x, lane = tid & 63, w = tid >> 6;
    const int bl = lane & 15, kg = lane >> 4;
    const int bg = blockIdx.x, ig = blockIdx.y;
    const int i0 = ig * 8, b0 = bg * 64;
    const int b  = b0 + w * 16 + bl;

    // ---------------- PHASE 1: issue ALL global loads ----------------
    bf16x8 afull[2][NJ];
    bf16x8 xv[2];
#pragma unroll
    for (int t4 = 0; t4 < 2; ++t4) {
        const int il = i0 + t4 * 4 + kg;   // this lane's input capsule
        const unsigned short* wbase = wb + (size_t)il * 128 + bl * 8;
#pragma unroll
        for (int j = 0; j < NJ; ++j)
            afull[t4][j] = *(const bf16x8*)(wbase + (size_t)j * (NI * 128));
        xv[t4] = *(const bf16x8*)(xb + ((size_t)b * NI + il) * 8);
    }
    f32x4 vs[NJ];
    if (MODE == 1) {
#pragma unroll
        for (int j = 0; j < NJ; ++j)
            vs[j] = *(const f32x4*)(vsum_g + (size_t)b * 160 + j * 16 + kg * 4);
    }
    // Pin: no compute may be scheduled before this point; all loads above
    // are issued back-to-back and overlap in the memory system.
    __builtin_amdgcn_sched_barrier(0);

    // ---------------- PHASE 2: compute ----------------
    const f32x4  zero  = {0.f, 0.f, 0.f, 0.f};
    const bf16x8 zerob = {0, 0, 0, 0, 0, 0, 0, 0};
    f32x4 sacc[NJ];
#pragma unroll
    for (int j = 0; j < NJ; ++j) sacc[j] = zero;

#pragma unroll
    for (int t4 = 0; t4 < 2; ++t4) {
        if (MODE == 0) {
#pragma unroll
            for (int j = 0; j < NJ; ++j)
                sacc[j] = __builtin_amdgcn_mfma_f32_16x16x32_bf16(afull[t4][j], xv[t4], sacc[j], 0, 0, 0);
        } else {
#pragma unroll
            for (int q = 0; q < 4; ++q) {
                const bf16x8 bq = (kg == q) ? xv[t4] : zerob;   // isolate i = i0+t4*4+q
                f32x4 uh[NJ];
#pragma unroll
                for (int j = 0; j < NJ; ++j)
                    uh[j] = __builtin_amdgcn_mfma_f32_16x16x32_bf16(afull[t4][j], bq, zero, 0, 0, 0);

                // per-lane partial dots over this lane's 4 d's (f32)
                float bd[NJ];
#pragma unroll
                for (int j = 0; j < NJ; ++j)
                    bd[j] = uh[j][0] * vs[j][0] + uh[j][1] * vs[j][1]
                          + uh[j][2] * vs[j][2] + uh[j][3] * vs[j][3];

                // fp16x2-packed butterfly over the 4 d-quad lane groups:
                // 10 shfl + 10 pk_add.
                h16x2 pk[5];
#pragma unroll
                for (int jp = 0; jp < 5; ++jp)
                    pk[jp] = __builtin_amdgcn_cvt_pkrtz(bd[2 * jp], bd[2 * jp + 1]);
#pragma unroll
                for (int jp = 0; jp < 5; ++jp) {
                    float f = __shfl_xor(__builtin_bit_cast(float, pk[jp]), 16, 64);
                    pk[jp] = pk[jp] + __builtin_bit_cast(h16x2, f);
                }
#pragma unroll
                for (int jp = 0; jp < 5; ++jp) {
                    float f = __shfl_xor(__builtin_bit_cast(float, pk[jp]), 32, 64);
                    pk[jp] = pk[jp] + __builtin_bit_cast(h16x2, f);
                }

                // softmax over j, no max-subtract (|logit| <= ~3, exp safe)
                float e[NJ];
#pragma unroll
                for (int jp = 0; jp < 5; ++jp) {
                    e[2 * jp]     = __expf((float)pk[jp][0]);
                    e[2 * jp + 1] = __expf((float)pk[jp][1]);
                }
                float Z = ((e[0] + e[1]) + (e[2] + e[3]))
                        + ((e[4] + e[5]) + (e[6] + e[7])) + (e[8] + e[9]);
                const float rZ = 1.f / Z;
#pragma unroll
                for (int j = 0; j < NJ; ++j) {
                    const float c = e[j] * rZ;
                    sacc[j] += c * uh[j];
                }
            }
        }
    }

    // epilogue: direct bf16 stores; lane (kg,bl) owns part[ig][b][j*16+kg*4..+4].
    // Per store-instr the wave covers 16 rows x 32B contiguous; the j-unroll
    // fully covers each 64B line back-to-back (L2 write-merge).
    unsigned short* pp = part + ((size_t)ig * NB + b) * 160;
#pragma unroll
    for (int j = 0; j < NJ; ++j) {
        ushort4 o;
        o.x = f2bf(sacc[j][0]); o.y = f2bf(sacc[j][1]);
        o.z = f2bf(sacc[j][2]); o.w = f2bf(sacc[j][3]);
        *(ushort4*)(pp + j * 16 + kg * 4) = o;
    }
}

// Sum 144 bf16 ig-partials, scale, squash over d (16-lane shfl), update vsum/out.
__global__ __launch_bounds__(256)
void squash_reduce(const unsigned short* __restrict__ part,
                   float* __restrict__ vsum_g, float* __restrict__ out,
                   float alpha, int mode)
{
    const int t = blockIdx.x * 256 + threadIdx.x;   // < 81920 = b*160 + j*16 + d
    const unsigned short* p = part + t;
    float a0 = 0.f, a1 = 0.f, a2 = 0.f, a3 = 0.f;
#pragma unroll 4
    for (int ig = 0; ig < NIGB; ig += 4) {
        a0 += bf2f(p[(size_t)ig * 81920]);
        a1 += bf2f(p[(size_t)(ig + 1) * 81920]);
        a2 += bf2f(p[(size_t)(ig + 2) * 81920]);
        a3 += bf2f(p[(size_t)(ig + 3) * 81920]);
    }
    const float s = ((a0 + a1) + (a2 + a3)) * alpha;

    float sq = s * s;
    sq += __shfl_xor(sq, 1, 64);
    sq += __shfl_xor(sq, 2, 64);
    sq += __shfl_xor(sq, 4, 64);
    sq += __shfl_xor(sq, 8, 64);
    const float sc = sq / ((1.f + sq) * sqrtf(sq + EPS_));
    const float v  = sc * s;

    if (mode == 0)      vsum_g[t] = v;
    else if (mode == 1) vsum_g[t] += v;
    else                out[t] = v;
}

extern "C" void kernel_launch(void* const* d_in, const int* in_sizes, int n_in,
                              void* d_out, int out_size, void* d_ws, size_t ws_size,
                              hipStream_t stream)
{
    const float* inp = (const float*)d_in[0];
    const float* Wg  = (const float*)d_in[1];
    float* out = (float*)d_out;

    unsigned short* xbp  = (unsigned short*)d_ws;
    unsigned short* wbp  = xbp + XB_ELEMS;
    unsigned short* part = wbp + WB_ELEMS;                    // [144][512][160] bf16
    float* vsum = (float*)(part + (size_t)NIGB * NB * 160);   // [512][10][16] f32

    conv_bf16<<<(XQ + WQ + 255) / 256, 256, 0, stream>>>(inp, Wg, xbp, wbp);

    dim3 grid(8, NIGB);   // (8,144) = 1152 blocks — R18/R24/R26 A/B baseline
    // iter 0: c uniform 1/10 (folded into alpha); K=32 contracts 4 i's exactly
    caps_pass<0><<<grid, 256, 0, stream>>>(xbp, wbp, nullptr, part);
    squash_reduce<<<320, 256, 0, stream>>>(part, vsum, out, 0.1f, 0);
    // iter 1: logits = u_hat . v0
    caps_pass<1><<<grid, 256, 0, stream>>>(xbp, wbp, vsum, part);
    squash_reduce<<<320, 256, 0, stream>>>(part, vsum, out, 1.0f, 1);
    // iter 2: logits = u_hat . (v0+v1)
    caps_pass<1><<<grid, 256, 0, stream>>>(xbp, wbp, vsum, part);
    squash_reduce<<<320, 256, 0, stream>>>(part, vsum, out, 1.0f, 2);
}